// Round 3
// baseline (606.451 us; speedup 1.0000x reference)
//
#include <hip/hip_runtime.h>
#include <hip/hip_bf16.h>
#include <math.h>

#define Bsz 256
#define Tn 32
#define CODEN 4880
#define MEDN 1000
#define Hdim 128
#define OUTN 4880
#define BT (Bsz*Tn)
#define R3H 384

// ---------------- kernel 1: Hc = tanh(c_emb @ W_c), Hm = tanh(m_emb @ W_m) ----
__global__ __launch_bounds__(128) void k_emb(
    const float* __restrict__ c_emb, const float* __restrict__ m_emb,
    const float* __restrict__ W_c, const float* __restrict__ W_m,
    float* __restrict__ Hc, float* __restrict__ Hm) {
  int row = blockIdx.x;
  const float* emb; const float* W; float* out;
  if (row < CODEN) { emb = c_emb + (size_t)row * Hdim; W = W_c; out = Hc + (size_t)row * Hdim; }
  else { int r = row - CODEN; emb = m_emb + (size_t)r * Hdim; W = W_m; out = Hm + (size_t)r * Hdim; }
  __shared__ float e[Hdim];
  int h = threadIdx.x;
  e[h] = emb[h];
  __syncthreads();
  float acc = 0.f;
#pragma unroll 8
  for (int k = 0; k < Hdim; ++k) acc += e[k] * W[k * Hdim + h];
  out[h] = tanhf(acc);
}

// ---------------- kernel 2: per-visit sparse aggregate + repre + attention score
#define MAXC 1024
#define MAXM 256

__global__ __launch_bounds__(256) void k_visit(
    const float* __restrict__ code_x, const float* __restrict__ med,
    const float* __restrict__ Hc, const float* __restrict__ Hm,
    const float* __restrict__ Wa, const float* __restrict__ ba,
    const float* __restrict__ va,
    float* __restrict__ repre, float* __restrict__ scores) {
  int bt = blockIdx.x;
  int tid = threadIdx.x;
  __shared__ int list_c[MAXC];
  __shared__ int list_m[MAXM];
  __shared__ int cnt_c, cnt_m;
  __shared__ float rep_s[R3H];
  __shared__ float red[256];
  if (tid == 0) { cnt_c = 0; cnt_m = 0; }
  __syncthreads();

  // phase 1: scan rows (coalesced float4), compact nonzero indices
  const float4* cx = (const float4*)(code_x + (size_t)bt * CODEN);
  for (int i = tid; i < CODEN / 4; i += 256) {
    float4 v = cx[i];
    if (v.x != 0.f) { int p = atomicAdd(&cnt_c, 1); if (p < MAXC) list_c[p] = 4*i; }
    if (v.y != 0.f) { int p = atomicAdd(&cnt_c, 1); if (p < MAXC) list_c[p] = 4*i+1; }
    if (v.z != 0.f) { int p = atomicAdd(&cnt_c, 1); if (p < MAXC) list_c[p] = 4*i+2; }
    if (v.w != 0.f) { int p = atomicAdd(&cnt_c, 1); if (p < MAXC) list_c[p] = 4*i+3; }
  }
  const float4* mx = (const float4*)(med + (size_t)bt * MEDN);
  for (int i = tid; i < MEDN / 4; i += 256) {
    float4 v = mx[i];
    if (v.x != 0.f) { int p = atomicAdd(&cnt_m, 1); if (p < MAXM) list_m[p] = 4*i; }
    if (v.y != 0.f) { int p = atomicAdd(&cnt_m, 1); if (p < MAXM) list_m[p] = 4*i+1; }
    if (v.z != 0.f) { int p = atomicAdd(&cnt_m, 1); if (p < MAXM) list_m[p] = 4*i+2; }
    if (v.w != 0.f) { int p = atomicAdd(&cnt_m, 1); if (p < MAXM) list_m[p] = 4*i+3; }
  }
  __syncthreads();
  int nc = cnt_c < MAXC ? cnt_c : MAXC;
  int nm = cnt_m < MAXM ? cnt_m : MAXM;

  // phase 2: gather-sum Hc/Hm rows. 256 threads = 2 halves x 128 h-lanes
  int h = tid & 127, half = tid >> 7;
  float accC = 0.f;
#pragma unroll 2
  for (int j = half; j < nc; j += 2) accC += Hc[(size_t)list_c[j] * Hdim + h];
  float accM = 0.f;
#pragma unroll 2
  for (int j = half; j < nm; j += 2) accM += Hm[(size_t)list_m[j] * Hdim + h];

  red[tid] = accC;
  __syncthreads();
  float hc = 0.f, hm = 0.f;
  if (half == 0) hc = (red[h] + red[h + 128]) / fmaxf((float)nc, 1.f);
  __syncthreads();
  red[tid] = accM;
  __syncthreads();
  if (half == 0) {
    hm = (red[h] + red[h + 128]) / fmaxf((float)nm, 1.f);
    rep_s[h] = hc;
    rep_s[Hdim + h] = hm;
    rep_s[2 * Hdim + h] = hc * hm;
  }
  __syncthreads();

  // write repre
  float* rp = repre + (size_t)bt * R3H;
  for (int i = tid; i < R3H; i += 256) rp[i] = rep_s[i];

  // fused attention score: score = va . tanh(rep @ Wa + ba)
  int j = tid & 31, kc = tid >> 5;  // 8 chunks of 48 k's
  float p = 0.f;
  int k0 = kc * 48;
#pragma unroll 8
  for (int k = k0; k < k0 + 48; ++k) p += rep_s[k] * Wa[k * 32 + j];
  __syncthreads();
  red[tid] = p;
  __syncthreads();
  if (tid < 32) {
    float tot = 0.f;
#pragma unroll
    for (int c = 0; c < 8; ++c) tot += red[c * 32 + tid];
    float u = tanhf(tot + ba[tid]);
    float sv = u * va[tid];
#pragma unroll
    for (int off = 16; off >= 1; off >>= 1) sv += __shfl_down(sv, off, 32);
    if (tid == 0) scores[bt] = sv;
  }
}

// ---------------- kernel 3: per-batch masked softmax + context -----------------
__global__ __launch_bounds__(128) void k_ctx(
    const float* __restrict__ scores, const int* __restrict__ lens,
    const float* __restrict__ repre, float* __restrict__ ctx) {
  int b = blockIdx.x, tid = threadIdx.x;
  __shared__ float attn[Tn];
  int len = lens[b];
  if (tid < Tn) {
    float s = scores[b * Tn + tid];
    bool valid = tid < len;
    float sm = valid ? s : -1e30f;
    float m = sm;
#pragma unroll
    for (int off = 16; off >= 1; off >>= 1) m = fmaxf(m, __shfl_xor(m, off, 32));
    float e = valid ? expf(sm - m) : 0.f;
    float sum = e;
#pragma unroll
    for (int off = 16; off >= 1; off >>= 1) sum += __shfl_xor(sum, off, 32);
    attn[tid] = e / sum;
  }
  __syncthreads();
  const float* rp = repre + (size_t)b * Tn * R3H;
  for (int d = tid; d < R3H; d += 128) {
    float a = 0.f;
#pragma unroll
    for (int t = 0; t < Tn; ++t) a += attn[t] * rp[t * R3H + d];
    ctx[(size_t)b * R3H + d] = a;
  }
}

// ---------------- kernel 4: out = sigmoid(ctx @ W_cls + b_cls) -----------------
// block: 256 threads, each thread 4 consecutive outputs (float4), 8 batch rows.
// grid: 5 o-tiles (1024 each) x 32 b-tiles (8 each) = 160 blocks.
#define FMA4(A, s, w) { A.x += (s)*(w).x; A.y += (s)*(w).y; A.z += (s)*(w).z; A.w += (s)*(w).w; }

__global__ __launch_bounds__(256) void k_cls(
    const float* __restrict__ ctx, const float* __restrict__ W_cls,
    const float* __restrict__ b_cls, float* __restrict__ out) {
  __shared__ float cs_t[R3H * 8];  // [k][r] transposed
  int tid = threadIdx.x;
  int ob = blockIdx.x % 5;
  int b0 = (blockIdx.x / 5) * 8;
  for (int i = tid; i < R3H * 8; i += 256) {
    int k = i >> 3, r = i & 7;
    cs_t[i] = ctx[(size_t)(b0 + r) * R3H + k];
  }
  __syncthreads();
  int o0 = ob * 1024 + tid * 4;
  if (o0 >= OUTN) return;
  float4 acc[8];
#pragma unroll
  for (int r = 0; r < 8; ++r) acc[r] = make_float4(0.f, 0.f, 0.f, 0.f);
  const float* wp = W_cls + o0;
#pragma unroll 2
  for (int k = 0; k < R3H; ++k) {
    float4 w = *(const float4*)(wp + (size_t)k * OUTN);
    float4 cA = *(const float4*)&cs_t[k * 8];
    float4 cB = *(const float4*)&cs_t[k * 8 + 4];
    FMA4(acc[0], cA.x, w); FMA4(acc[1], cA.y, w);
    FMA4(acc[2], cA.z, w); FMA4(acc[3], cA.w, w);
    FMA4(acc[4], cB.x, w); FMA4(acc[5], cB.y, w);
    FMA4(acc[6], cB.z, w); FMA4(acc[7], cB.w, w);
  }
  float4 bc = *(const float4*)(b_cls + o0);
#pragma unroll
  for (int r = 0; r < 8; ++r) {
    float4 v;
    v.x = 1.f / (1.f + expf(-(acc[r].x + bc.x)));
    v.y = 1.f / (1.f + expf(-(acc[r].y + bc.y)));
    v.z = 1.f / (1.f + expf(-(acc[r].z + bc.z)));
    v.w = 1.f / (1.f + expf(-(acc[r].w + bc.w)));
    *(float4*)(out + (size_t)(b0 + r) * OUTN + o0) = v;
  }
}

// ---------------- launch -------------------------------------------------------
extern "C" void kernel_launch(void* const* d_in, const int* in_sizes, int n_in,
                              void* d_out, int out_size, void* d_ws, size_t ws_size,
                              hipStream_t stream) {
  const float* code_x = (const float*)d_in[0];
  // d_in[1] = divided   (unused)
  // d_in[2] = neighbors (unused)
  const int*   lens   = (const int*)d_in[3];
  const float* med    = (const float*)d_in[4];
  const float* c_emb  = (const float*)d_in[5];
  const float* m_emb  = (const float*)d_in[6];
  const float* W_c    = (const float*)d_in[7];
  const float* W_m    = (const float*)d_in[8];
  const float* Wa     = (const float*)d_in[9];
  const float* ba     = (const float*)d_in[10];
  const float* va     = (const float*)d_in[11];
  const float* W_cls  = (const float*)d_in[12];
  const float* b_cls  = (const float*)d_in[13];
  float* out = (float*)d_out;
  float* ws  = (float*)d_ws;

  float* Hc     = ws;                     // 4880*128 = 624640
  float* Hm     = ws + 624640;            // 1000*128 = 128000
  float* repre  = ws + 752640;            // 8192*384 = 3145728
  float* scores = ws + 3898368;           // 8192
  float* ctx    = ws + 3906560;           // 256*384 = 98304

  hipLaunchKernelGGL(k_emb,   dim3(CODEN + MEDN), dim3(128), 0, stream,
                     c_emb, m_emb, W_c, W_m, Hc, Hm);
  hipLaunchKernelGGL(k_visit, dim3(BT), dim3(256), 0, stream,
                     code_x, med, Hc, Hm, Wa, ba, va, repre, scores);
  hipLaunchKernelGGL(k_ctx,   dim3(Bsz), dim3(128), 0, stream,
                     scores, lens, repre, ctx);
  hipLaunchKernelGGL(k_cls,   dim3(160), dim3(256), 0, stream,
                     ctx, W_cls, b_cls, out);
}

// Round 5
// 535.810 us; speedup vs baseline: 1.1318x; 1.1318x over previous
//
#include <hip/hip_runtime.h>
#include <hip/hip_bf16.h>
#include <math.h>

#define Bsz 256
#define Tn 32
#define CODEN 4880
#define MEDN 1000
#define Hdim 128
#define OUTN 4880
#define BT (Bsz*Tn)
#define R3H 384
#define NC4 (CODEN/4)   // 1220
#define NM4 (MEDN/4)    // 250

__device__ inline int mbcnt64(unsigned long long m) {
  return __builtin_amdgcn_mbcnt_hi((unsigned)(m >> 32),
         __builtin_amdgcn_mbcnt_lo((unsigned)m, 0));
}

__device__ inline unsigned f2bf(float f) {  // RNE fp32->bf16 (finite inputs)
  unsigned u = __float_as_uint(f);
  return (u + 0x7fffu + ((u >> 16) & 1u)) >> 16;
}

// ---------------- kernel 1: Hc2 = pack_bf16(tanh(c_emb @ W_c)), Hm2 likewise --
__global__ __launch_bounds__(128) void k_emb(
    const float* __restrict__ c_emb, const float* __restrict__ m_emb,
    const float* __restrict__ W_c, const float* __restrict__ W_m,
    unsigned* __restrict__ Hc2, unsigned* __restrict__ Hm2) {
  int row = blockIdx.x;
  const float* emb; const float* W; unsigned* out2;
  if (row < CODEN) { emb = c_emb + (size_t)row * Hdim; W = W_c; out2 = Hc2 + (size_t)row * 64; }
  else { int r = row - CODEN; emb = m_emb + (size_t)r * Hdim; W = W_m; out2 = Hm2 + (size_t)r * 64; }
  __shared__ float e[Hdim];
  int h = threadIdx.x;
  e[h] = emb[h];
  __syncthreads();
  float acc = 0.f;
#pragma unroll 8
  for (int k = 0; k < Hdim; ++k) acc += e[k] * W[k * Hdim + h];
  float vme = tanhf(acc);
  float vnx = __shfl_down(vme, 1, 64);   // pairs (2t,2t+1) are within one wave
  if ((h & 1) == 0) out2[h >> 1] = f2bf(vme) | (f2bf(vnx) << 16);
}

// ---------------- kernel 2: per-visit sparse aggregate + repre + attention score
#define MAXC 1024
#define MAXM 256

__global__ __launch_bounds__(256) void k_visit(
    const float* __restrict__ code_x, const float* __restrict__ med,
    const unsigned* __restrict__ Hc2, const unsigned* __restrict__ Hm2,
    const float* __restrict__ Wa, const float* __restrict__ ba,
    const float* __restrict__ va,
    float* __restrict__ repre, float* __restrict__ scores) {
  int bt = blockIdx.x;
  int tid = threadIdx.x;
  int lane = tid & 63;
  __shared__ int list_c[MAXC];
  __shared__ int list_m[MAXM];
  __shared__ int cnt_c, cnt_m;
  __shared__ float rep_s[R3H];
  __shared__ float red[512];
  if (tid == 0) { cnt_c = 0; cnt_m = 0; }
  __syncthreads();

  // ---- phase 1: scan + ballot-based compaction (1 LDS atomic per wave/iter) --
  const float4* cx = (const float4*)(code_x + (size_t)bt * CODEN);
#pragma unroll
  for (int it = 0; it < 5; ++it) {
    int i = it * 256 + tid;
    float4 v = make_float4(0.f, 0.f, 0.f, 0.f);
    if (i < NC4) v = cx[i];
    unsigned long long m0 = __ballot(v.x != 0.f);
    unsigned long long m1 = __ballot(v.y != 0.f);
    unsigned long long m2 = __ballot(v.z != 0.f);
    unsigned long long m3 = __ballot(v.w != 0.f);
    int c0 = __popcll(m0), c1 = __popcll(m1), c2 = __popcll(m2), c3 = __popcll(m3);
    int base = 0;
    if (lane == 0) base = atomicAdd(&cnt_c, c0 + c1 + c2 + c3);
    base = __builtin_amdgcn_readfirstlane(base);
    int p;
    p = base + mbcnt64(m0);           if (v.x != 0.f && p < MAXC) list_c[p] = 4*i;
    p = base + c0 + mbcnt64(m1);      if (v.y != 0.f && p < MAXC) list_c[p] = 4*i+1;
    p = base + c0+c1 + mbcnt64(m2);   if (v.z != 0.f && p < MAXC) list_c[p] = 4*i+2;
    p = base + c0+c1+c2 + mbcnt64(m3);if (v.w != 0.f && p < MAXC) list_c[p] = 4*i+3;
  }
  {
    const float4* mx = (const float4*)(med + (size_t)bt * MEDN);
    int i = tid;
    float4 v = make_float4(0.f, 0.f, 0.f, 0.f);
    if (i < NM4) v = mx[i];
    unsigned long long m0 = __ballot(v.x != 0.f);
    unsigned long long m1 = __ballot(v.y != 0.f);
    unsigned long long m2 = __ballot(v.z != 0.f);
    unsigned long long m3 = __ballot(v.w != 0.f);
    int c0 = __popcll(m0), c1 = __popcll(m1), c2 = __popcll(m2), c3 = __popcll(m3);
    int base = 0;
    if (lane == 0) base = atomicAdd(&cnt_m, c0 + c1 + c2 + c3);
    base = __builtin_amdgcn_readfirstlane(base);
    int p;
    p = base + mbcnt64(m0);           if (v.x != 0.f && p < MAXM) list_m[p] = 4*i;
    p = base + c0 + mbcnt64(m1);      if (v.y != 0.f && p < MAXM) list_m[p] = 4*i+1;
    p = base + c0+c1 + mbcnt64(m2);   if (v.z != 0.f && p < MAXM) list_m[p] = 4*i+2;
    p = base + c0+c1+c2 + mbcnt64(m3);if (v.w != 0.f && p < MAXM) list_m[p] = 4*i+3;
  }
  __syncthreads();
  int nc = cnt_c < MAXC ? cnt_c : MAXC;
  int nm = cnt_m < MAXM ? cnt_m : MAXM;

  // ---- phase 2: bf16 gather-sum. 4 groups x 64 lanes, each lane one h-pair --
  int g = tid >> 6, t = lane;
  float aCx = 0.f, aCy = 0.f;
#pragma unroll 4
  for (int j = g; j < nc; j += 4) {
    unsigned v = Hc2[(size_t)list_c[j] * 64 + t];
    aCx += __uint_as_float(v << 16);
    aCy += __uint_as_float(v & 0xffff0000u);
  }
  float aMx = 0.f, aMy = 0.f;
#pragma unroll 4
  for (int j = g; j < nm; j += 4) {
    unsigned v = Hm2[(size_t)list_m[j] * 64 + t];
    aMx += __uint_as_float(v << 16);
    aMy += __uint_as_float(v & 0xffff0000u);
  }

  // reduce across the 4 groups: red[g*128 + h], h = 2t + comp
  red[g * 128 + 2 * t]     = aCx;
  red[g * 128 + 2 * t + 1] = aCy;
  __syncthreads();
  float hc = 0.f, hm = 0.f;
  if (tid < 128) {
    float s = red[tid] + red[128 + tid] + red[256 + tid] + red[384 + tid];
    hc = s / fmaxf((float)nc, 1.f);
  }
  __syncthreads();
  red[g * 128 + 2 * t]     = aMx;
  red[g * 128 + 2 * t + 1] = aMy;
  __syncthreads();
  if (tid < 128) {
    float s = red[tid] + red[128 + tid] + red[256 + tid] + red[384 + tid];
    hm = s / fmaxf((float)nm, 1.f);
    rep_s[tid]             = hc;
    rep_s[Hdim + tid]      = hm;
    rep_s[2 * Hdim + tid]  = hc * hm;
  }
  __syncthreads();

  // write repre
  float* rp = repre + (size_t)bt * R3H;
  for (int i = tid; i < R3H; i += 256) rp[i] = rep_s[i];

  // fused attention score: score = va . tanh(rep @ Wa + ba)
  int j = tid & 31, kc = tid >> 5;  // 8 chunks of 48 k's
  float pacc = 0.f;
  int k0 = kc * 48;
#pragma unroll 8
  for (int k = k0; k < k0 + 48; ++k) pacc += rep_s[k] * Wa[k * 32 + j];
  __syncthreads();
  red[tid] = pacc;
  __syncthreads();
  if (tid < 32) {
    float tot = 0.f;
#pragma unroll
    for (int c = 0; c < 8; ++c) tot += red[c * 32 + tid];
    float u = tanhf(tot + ba[tid]);
    float sv = u * va[tid];
#pragma unroll
    for (int off = 16; off >= 1; off >>= 1) sv += __shfl_down(sv, off, 32);
    if (tid == 0) scores[bt] = sv;
  }
}

// ---------------- kernel 3: per-batch masked softmax + context -----------------
__global__ __launch_bounds__(128) void k_ctx(
    const float* __restrict__ scores, const int* __restrict__ lens,
    const float* __restrict__ repre, float* __restrict__ ctx) {
  int b = blockIdx.x, tid = threadIdx.x;
  __shared__ float attn[Tn];
  int len = lens[b];
  if (tid < Tn) {
    float s = scores[b * Tn + tid];
    bool valid = tid < len;
    float sm = valid ? s : -1e30f;
    float m = sm;
#pragma unroll
    for (int off = 16; off >= 1; off >>= 1) m = fmaxf(m, __shfl_xor(m, off, 32));
    float e = valid ? expf(sm - m) : 0.f;
    float sum = e;
#pragma unroll
    for (int off = 16; off >= 1; off >>= 1) sum += __shfl_xor(sum, off, 32);
    attn[tid] = e / sum;
  }
  __syncthreads();
  const float* rp = repre + (size_t)b * Tn * R3H;
  for (int d = tid; d < R3H; d += 128) {
    float a = 0.f;
#pragma unroll
    for (int t = 0; t < Tn; ++t) a += attn[t] * rp[t * R3H + d];
    ctx[(size_t)b * R3H + d] = a;
  }
}

// ---------------- kernel 4: out = sigmoid(ctx @ W_cls + b_cls) -----------------
// 256 threads, thread = 4 consecutive outputs (float4) x 8 batch rows.
// grid: 5 o-tiles (1024) x 32 b-tiles (8) = 160 blocks. 8-deep load batches.
__device__ inline void fma4(float4& a, float s, const float4& w) {
  a.x += s * w.x; a.y += s * w.y; a.z += s * w.z; a.w += s * w.w;
}

__global__ __launch_bounds__(256) void k_cls(
    const float* __restrict__ ctx, const float* __restrict__ W_cls,
    const float* __restrict__ b_cls, float* __restrict__ out) {
  __shared__ float cs_t[R3H * 8];  // [k][r] transposed
  int tid = threadIdx.x;
  int ob = blockIdx.x % 5;
  int b0 = (blockIdx.x / 5) * 8;
  for (int i = tid; i < R3H * 8; i += 256) {
    int k = i >> 3, r = i & 7;
    cs_t[i] = ctx[(size_t)(b0 + r) * R3H + k];
  }
  __syncthreads();
  int o0 = ob * 1024 + tid * 4;
  if (o0 >= OUTN) return;
  float4 acc[8];
#pragma unroll
  for (int r = 0; r < 8; ++r) acc[r] = make_float4(0.f, 0.f, 0.f, 0.f);
  const float* wp = W_cls + o0;
  for (int k = 0; k < R3H; k += 8) {
    float4 wv[8];
#pragma unroll
    for (int u = 0; u < 8; ++u) wv[u] = *(const float4*)(wp + (size_t)(k + u) * OUTN);
#pragma unroll
    for (int u = 0; u < 8; ++u) {
      float4 cA = *(const float4*)&cs_t[(k + u) * 8];
      float4 cB = *(const float4*)&cs_t[(k + u) * 8 + 4];
      fma4(acc[0], cA.x, wv[u]); fma4(acc[1], cA.y, wv[u]);
      fma4(acc[2], cA.z, wv[u]); fma4(acc[3], cA.w, wv[u]);
      fma4(acc[4], cB.x, wv[u]); fma4(acc[5], cB.y, wv[u]);
      fma4(acc[6], cB.z, wv[u]); fma4(acc[7], cB.w, wv[u]);
    }
  }
  float4 bc = *(const float4*)(b_cls + o0);
#pragma unroll
  for (int r = 0; r < 8; ++r) {
    float4 v;
    v.x = 1.f / (1.f + expf(-(acc[r].x + bc.x)));
    v.y = 1.f / (1.f + expf(-(acc[r].y + bc.y)));
    v.z = 1.f / (1.f + expf(-(acc[r].z + bc.z)));
    v.w = 1.f / (1.f + expf(-(acc[r].w + bc.w)));
    *(float4*)(out + (size_t)(b0 + r) * OUTN + o0) = v;
  }
}

// ---------------- launch -------------------------------------------------------
extern "C" void kernel_launch(void* const* d_in, const int* in_sizes, int n_in,
                              void* d_out, int out_size, void* d_ws, size_t ws_size,
                              hipStream_t stream) {
  const float* code_x = (const float*)d_in[0];
  // d_in[1] = divided   (unused)
  // d_in[2] = neighbors (unused)
  const int*   lens   = (const int*)d_in[3];
  const float* med    = (const float*)d_in[4];
  const float* c_emb  = (const float*)d_in[5];
  const float* m_emb  = (const float*)d_in[6];
  const float* W_c    = (const float*)d_in[7];
  const float* W_m    = (const float*)d_in[8];
  const float* Wa     = (const float*)d_in[9];
  const float* ba     = (const float*)d_in[10];
  const float* va     = (const float*)d_in[11];
  const float* W_cls  = (const float*)d_in[12];
  const float* b_cls  = (const float*)d_in[13];
  float* out = (float*)d_out;
  float* ws  = (float*)d_ws;

  unsigned* Hc2    = (unsigned*)ws;                    // 4880*64 = 312320 u32
  unsigned* Hm2    = (unsigned*)ws + 312320;           // 1000*64 = 64000 u32
  float*    repre  = ws + 376320;                      // 8192*384 = 3145728
  float*    scores = ws + 3522048;                     // 8192
  float*    ctx    = ws + 3530240;                     // 256*384 = 98304

  hipLaunchKernelGGL(k_emb,   dim3(CODEN + MEDN), dim3(128), 0, stream,
                     c_emb, m_emb, W_c, W_m, Hc2, Hm2);
  hipLaunchKernelGGL(k_visit, dim3(BT), dim3(256), 0, stream,
                     code_x, med, Hc2, Hm2, Wa, ba, va, repre, scores);
  hipLaunchKernelGGL(k_ctx,   dim3(Bsz), dim3(128), 0, stream,
                     scores, lens, repre, ctx);
  hipLaunchKernelGGL(k_cls,   dim3(160), dim3(256), 0, stream,
                     ctx, W_cls, b_cls, out);
}

// Round 6
// 533.097 us; speedup vs baseline: 1.1376x; 1.0051x over previous
//
#include <hip/hip_runtime.h>
#include <hip/hip_bf16.h>
#include <math.h>

#define Bsz 256
#define Tn 32
#define CODEN 4880
#define MEDN 1000
#define Hdim 128
#define OUTN 4880
#define BT (Bsz*Tn)
#define R3H 384
#define NC4 (CODEN/4)   // 1220
#define NM4 (MEDN/4)    // 250

typedef __attribute__((ext_vector_type(4))) float f32x4;

__device__ inline int mbcnt64(unsigned long long m) {
  return __builtin_amdgcn_mbcnt_hi((unsigned)(m >> 32),
         __builtin_amdgcn_mbcnt_lo((unsigned)m, 0));
}

__device__ inline unsigned f2bf(float f) {  // RNE fp32->bf16 (finite inputs)
  unsigned u = __float_as_uint(f);
  return (u + 0x7fffu + ((u >> 16) & 1u)) >> 16;
}

// ---------------- kernel 1: Hc2 = pack_bf16(tanh(c_emb @ W_c)), Hm2 likewise --
__global__ __launch_bounds__(128) void k_emb(
    const float* __restrict__ c_emb, const float* __restrict__ m_emb,
    const float* __restrict__ W_c, const float* __restrict__ W_m,
    unsigned* __restrict__ Hc2, unsigned* __restrict__ Hm2) {
  int row = blockIdx.x;
  const float* emb; const float* W; unsigned* out2;
  if (row < CODEN) { emb = c_emb + (size_t)row * Hdim; W = W_c; out2 = Hc2 + (size_t)row * 64; }
  else { int r = row - CODEN; emb = m_emb + (size_t)r * Hdim; W = W_m; out2 = Hm2 + (size_t)r * 64; }
  __shared__ float e[Hdim];
  int h = threadIdx.x;
  e[h] = emb[h];
  __syncthreads();
  float acc = 0.f;
#pragma unroll 8
  for (int k = 0; k < Hdim; ++k) acc += e[k] * W[k * Hdim + h];
  float vme = tanhf(acc);
  float vnx = __shfl_down(vme, 1, 64);   // pairs (2t,2t+1) are within one wave
  if ((h & 1) == 0) out2[h >> 1] = f2bf(vme) | (f2bf(vnx) << 16);
}

// ---------------- kernel 2: per-visit sparse aggregate + repre + attention score
#define MAXC 1024
#define MAXM 256

__global__ __launch_bounds__(512) void k_visit(
    const float* __restrict__ code_x, const float* __restrict__ med,
    const unsigned* __restrict__ Hc2, const unsigned* __restrict__ Hm2,
    const float* __restrict__ Wa, const float* __restrict__ ba,
    const float* __restrict__ va,
    float* __restrict__ repre, float* __restrict__ scores) {
  int bt = blockIdx.x;
  int tid = threadIdx.x;
  int lane = tid & 63;
  __shared__ int list_c[MAXC];
  __shared__ int list_m[MAXM];
  __shared__ int cnt_c, cnt_m;
  __shared__ float rep_s[R3H];
  __shared__ float red[2048];   // 16 groups x 128 h
  if (tid == 0) { cnt_c = 0; cnt_m = 0; }
  __syncthreads();

  // ---- phase 1: scan + ballot compaction (1 LDS atomic per wave per iter) ----
  const uint4* cx = (const uint4*)(code_x + (size_t)bt * CODEN);
#pragma unroll
  for (int it = 0; it < 3; ++it) {
    int i = it * 512 + tid;
    uint4 v = make_uint4(0u, 0u, 0u, 0u);
    if (i < NC4) v = cx[i];
    unsigned long long m0 = __ballot(v.x != 0u);
    unsigned long long m1 = __ballot(v.y != 0u);
    unsigned long long m2 = __ballot(v.z != 0u);
    unsigned long long m3 = __ballot(v.w != 0u);
    int c0 = __popcll(m0), c1 = __popcll(m1), c2 = __popcll(m2), c3 = __popcll(m3);
    int base = 0;
    if (lane == 0) base = atomicAdd(&cnt_c, c0 + c1 + c2 + c3);
    base = __builtin_amdgcn_readfirstlane(base);
    int p;
    p = base + mbcnt64(m0);            if (v.x != 0u && p < MAXC) list_c[p] = 4*i;
    p = base + c0 + mbcnt64(m1);       if (v.y != 0u && p < MAXC) list_c[p] = 4*i+1;
    p = base + c0+c1 + mbcnt64(m2);    if (v.z != 0u && p < MAXC) list_c[p] = 4*i+2;
    p = base + c0+c1+c2 + mbcnt64(m3); if (v.w != 0u && p < MAXC) list_c[p] = 4*i+3;
  }
  {
    const uint4* mx = (const uint4*)(med + (size_t)bt * MEDN);
    int i = tid;
    uint4 v = make_uint4(0u, 0u, 0u, 0u);
    if (i < NM4) v = mx[i];
    unsigned long long m0 = __ballot(v.x != 0u);
    unsigned long long m1 = __ballot(v.y != 0u);
    unsigned long long m2 = __ballot(v.z != 0u);
    unsigned long long m3 = __ballot(v.w != 0u);
    int c0 = __popcll(m0), c1 = __popcll(m1), c2 = __popcll(m2), c3 = __popcll(m3);
    int base = 0;
    if (lane == 0) base = atomicAdd(&cnt_m, c0 + c1 + c2 + c3);
    base = __builtin_amdgcn_readfirstlane(base);
    int p;
    p = base + mbcnt64(m0);            if (v.x != 0u && p < MAXM) list_m[p] = 4*i;
    p = base + c0 + mbcnt64(m1);       if (v.y != 0u && p < MAXM) list_m[p] = 4*i+1;
    p = base + c0+c1 + mbcnt64(m2);    if (v.z != 0u && p < MAXM) list_m[p] = 4*i+2;
    p = base + c0+c1+c2 + mbcnt64(m3); if (v.w != 0u && p < MAXM) list_m[p] = 4*i+3;
  }
  __syncthreads();
  int nc = cnt_c < MAXC ? cnt_c : MAXC;
  int nm = cnt_m < MAXM ? cnt_m : MAXM;

  // ---- phase 2: bf16 gather. 16 groups x 32 lanes; lane holds h=4t..4t+3 ----
  int g = tid >> 5, t = tid & 31;
  unsigned toff = (unsigned)t << 3;           // byte offset of lane's uint2 in row
  const char* cb = (const char*)Hc2;
  f32x4 aC = {0.f, 0.f, 0.f, 0.f};
#pragma unroll 4
  for (int j = g; j < nc; j += 16) {
    unsigned off = ((unsigned)list_c[j] << 8) + toff;   // row*256B + lane*8B
    uint2 v = *(const uint2*)(cb + off);
    f32x4 d = { __uint_as_float(v.x << 16), __uint_as_float(v.x & 0xffff0000u),
                __uint_as_float(v.y << 16), __uint_as_float(v.y & 0xffff0000u) };
    aC += d;
  }
  const char* mb = (const char*)Hm2;
  f32x4 aM = {0.f, 0.f, 0.f, 0.f};
  for (int j = g; j < nm; j += 16) {
    unsigned off = ((unsigned)list_m[j] << 8) + toff;
    uint2 v = *(const uint2*)(mb + off);
    f32x4 d = { __uint_as_float(v.x << 16), __uint_as_float(v.x & 0xffff0000u),
                __uint_as_float(v.y << 16), __uint_as_float(v.y & 0xffff0000u) };
    aM += d;
  }

  // ---- reduce across 16 groups ------------------------------------------------
  ((f32x4*)red)[g * 32 + t] = aC;   // red[g*128 + 4t .. +3]
  __syncthreads();
  float hc = 0.f, hm = 0.f;
  if (tid < 128) {
    float s = 0.f;
#pragma unroll
    for (int gg = 0; gg < 16; ++gg) s += red[gg * 128 + tid];
    hc = s / fmaxf((float)nc, 1.f);
  }
  __syncthreads();
  ((f32x4*)red)[g * 32 + t] = aM;
  __syncthreads();
  if (tid < 128) {
    float s = 0.f;
#pragma unroll
    for (int gg = 0; gg < 16; ++gg) s += red[gg * 128 + tid];
    hm = s / fmaxf((float)nm, 1.f);
    rep_s[tid]            = hc;
    rep_s[Hdim + tid]     = hm;
    rep_s[2 * Hdim + tid] = hc * hm;
  }
  __syncthreads();

  // write repre
  float* rp = repre + (size_t)bt * R3H;
  if (tid < R3H) rp[tid] = rep_s[tid];

  // fused attention score: score = va . tanh(rep @ Wa + ba)
  int j = tid & 31, kc = tid >> 5;  // 16 chunks of 24 k's
  float pacc = 0.f;
  int k0 = kc * 24;
#pragma unroll 8
  for (int k = k0; k < k0 + 24; ++k) pacc += rep_s[k] * Wa[k * 32 + j];
  __syncthreads();
  red[tid] = pacc;
  __syncthreads();
  if (tid < 32) {
    float tot = 0.f;
#pragma unroll
    for (int c = 0; c < 16; ++c) tot += red[c * 32 + tid];
    float u = tanhf(tot + ba[tid]);
    float sv = u * va[tid];
#pragma unroll
    for (int off = 16; off >= 1; off >>= 1) sv += __shfl_down(sv, off, 32);
    if (tid == 0) scores[bt] = sv;
  }
}

// ---------------- kernel 3: per-batch masked softmax + context -----------------
__global__ __launch_bounds__(128) void k_ctx(
    const float* __restrict__ scores, const int* __restrict__ lens,
    const float* __restrict__ repre, float* __restrict__ ctx) {
  int b = blockIdx.x, tid = threadIdx.x;
  __shared__ float attn[Tn];
  int len = lens[b];
  if (tid < Tn) {
    float s = scores[b * Tn + tid];
    bool valid = tid < len;
    float sm = valid ? s : -1e30f;
    float m = sm;
#pragma unroll
    for (int off = 16; off >= 1; off >>= 1) m = fmaxf(m, __shfl_xor(m, off, 32));
    float e = valid ? expf(sm - m) : 0.f;
    float sum = e;
#pragma unroll
    for (int off = 16; off >= 1; off >>= 1) sum += __shfl_xor(sum, off, 32);
    attn[tid] = e / sum;
  }
  __syncthreads();
  const float* rp = repre + (size_t)b * Tn * R3H;
  for (int d = tid; d < R3H; d += 128) {
    float a = 0.f;
#pragma unroll
    for (int t = 0; t < Tn; ++t) a += attn[t] * rp[t * R3H + d];
    ctx[(size_t)b * R3H + d] = a;
  }
}

// ---------------- kernel 4: out = sigmoid(ctx @ W_cls + b_cls) -----------------
__device__ inline void fma4(float4& a, float s, const float4& w) {
  a.x += s * w.x; a.y += s * w.y; a.z += s * w.z; a.w += s * w.w;
}

__global__ __launch_bounds__(256) void k_cls(
    const float* __restrict__ ctx, const float* __restrict__ W_cls,
    const float* __restrict__ b_cls, float* __restrict__ out) {
  __shared__ float cs_t[R3H * 8];  // [k][r] transposed
  int tid = threadIdx.x;
  int ob = blockIdx.x % 5;
  int b0 = (blockIdx.x / 5) * 8;
  for (int i = tid; i < R3H * 8; i += 256) {
    int k = i >> 3, r = i & 7;
    cs_t[i] = ctx[(size_t)(b0 + r) * R3H + k];
  }
  __syncthreads();
  int o0 = ob * 1024 + tid * 4;
  if (o0 >= OUTN) return;
  float4 acc[8];
#pragma unroll
  for (int r = 0; r < 8; ++r) acc[r] = make_float4(0.f, 0.f, 0.f, 0.f);
  const float* wp = W_cls + o0;
  for (int k = 0; k < R3H; k += 8) {
    float4 wv[8];
#pragma unroll
    for (int u = 0; u < 8; ++u) wv[u] = *(const float4*)(wp + (size_t)(k + u) * OUTN);
#pragma unroll
    for (int u = 0; u < 8; ++u) {
      float4 cA = *(const float4*)&cs_t[(k + u) * 8];
      float4 cB = *(const float4*)&cs_t[(k + u) * 8 + 4];
      fma4(acc[0], cA.x, wv[u]); fma4(acc[1], cA.y, wv[u]);
      fma4(acc[2], cA.z, wv[u]); fma4(acc[3], cA.w, wv[u]);
      fma4(acc[4], cB.x, wv[u]); fma4(acc[5], cB.y, wv[u]);
      fma4(acc[6], cB.z, wv[u]); fma4(acc[7], cB.w, wv[u]);
    }
  }
  float4 bc = *(const float4*)(b_cls + o0);
#pragma unroll
  for (int r = 0; r < 8; ++r) {
    float4 v;
    v.x = 1.f / (1.f + expf(-(acc[r].x + bc.x)));
    v.y = 1.f / (1.f + expf(-(acc[r].y + bc.y)));
    v.z = 1.f / (1.f + expf(-(acc[r].z + bc.z)));
    v.w = 1.f / (1.f + expf(-(acc[r].w + bc.w)));
    *(float4*)(out + (size_t)(b0 + r) * OUTN + o0) = v;
  }
}

// ---------------- launch -------------------------------------------------------
extern "C" void kernel_launch(void* const* d_in, const int* in_sizes, int n_in,
                              void* d_out, int out_size, void* d_ws, size_t ws_size,
                              hipStream_t stream) {
  const float* code_x = (const float*)d_in[0];
  // d_in[1] = divided   (unused)
  // d_in[2] = neighbors (unused)
  const int*   lens   = (const int*)d_in[3];
  const float* med    = (const float*)d_in[4];
  const float* c_emb  = (const float*)d_in[5];
  const float* m_emb  = (const float*)d_in[6];
  const float* W_c    = (const float*)d_in[7];
  const float* W_m    = (const float*)d_in[8];
  const float* Wa     = (const float*)d_in[9];
  const float* ba     = (const float*)d_in[10];
  const float* va     = (const float*)d_in[11];
  const float* W_cls  = (const float*)d_in[12];
  const float* b_cls  = (const float*)d_in[13];
  float* out = (float*)d_out;
  float* ws  = (float*)d_ws;

  unsigned* Hc2    = (unsigned*)ws;                    // 4880*64 u32
  unsigned* Hm2    = (unsigned*)ws + 312320;           // 1000*64 u32
  float*    repre  = ws + 376320;                      // 8192*384
  float*    scores = ws + 3522048;                     // 8192
  float*    ctx    = ws + 3530240;                     // 256*384

  hipLaunchKernelGGL(k_emb,   dim3(CODEN + MEDN), dim3(128), 0, stream,
                     c_emb, m_emb, W_c, W_m, Hc2, Hm2);
  hipLaunchKernelGGL(k_visit, dim3(BT), dim3(512), 0, stream,
                     code_x, med, Hc2, Hm2, Wa, ba, va, repre, scores);
  hipLaunchKernelGGL(k_ctx,   dim3(Bsz), dim3(128), 0, stream,
                     scores, lens, repre, ctx);
  hipLaunchKernelGGL(k_cls,   dim3(160), dim3(256), 0, stream,
                     ctx, W_cls, b_cls, out);
}